// Round 1
// baseline (3368.124 us; speedup 1.0000x reference)
//
#include <hip/hip_runtime.h>
#include <hip/hip_cooperative_groups.h>

namespace cg = cooperative_groups;

#define IDX_BITS 20
#define IDX_MASK ((1u << IDX_BITS) - 1)

struct Ctx {
  const int* __restrict__ neighs;
  const float* __restrict__ hier;
  const int* __restrict__ row_splits;
  int V, K, nseg;
  unsigned long long* pri;         // [V] packed priority (smaller = earlier)
  unsigned long long* assign_pri;  // [V] min pri over centres containing u
  unsigned long long* centre_pri;  // [V]
  int* blocked_tag;                // [V] round tag
  int* state;                      // [V] 0=undecided 1=centre 2=dead
  int* listA;                      // [V] frontier ping
  int* listB;                      // [V] frontier pong
  int* centre_v;                   // [V]
  int* rank_of;                    // [V]
  int* cnt;                        // [64]: 0/1 alive counters, 2 centre count, 4+s seg counts
  int* out_sel;
  int* out_rs;
  int* out_gg;
};

__global__ void __launch_bounds__(256, 1) cluster_kernel(Ctx c) {
  cg::grid_group grid = cg::this_grid();
  const int tid = blockIdx.x * blockDim.x + threadIdx.x;
  const int nthr = gridDim.x * blockDim.x;
  const int V = c.V, K = c.K;

  // ---------------- init ----------------
  for (int v = tid; v < V; v += nthr) {
    unsigned int bits = __float_as_uint(c.hier[v]);
    unsigned int flip = ~bits;  // hier >= 0: bigger float = bigger bits; flip -> descending
    int seg = 0;
    for (int s = 1; s < c.nseg; ++s)
      if (v >= c.row_splits[s]) seg = s;
    unsigned long long p = ((unsigned long long)seg << (IDX_BITS + 32)) |
                           ((unsigned long long)flip << IDX_BITS) |
                           (unsigned int)v;
    c.pri[v] = p;
    c.assign_pri[v] = ~0ull;
    c.blocked_tag[v] = -1;
    c.state[v] = 0;
    c.out_sel[v] = -1;
  }
  if (tid < 64) c.cnt[tid] = 0;
  __threadfence();
  grid.sync();

  // ---------------- rounds ----------------
  int aliveN = V;
  int r = 0;
  while (true) {
    const int* lin = (r & 1) ? c.listB : c.listA;  // r==0 uses implicit identity
    int* lout = (r & 1) ? c.listA : c.listB;

    // phase B: undecided c blocks later out-neighbours (plain tag writes)
    {
      const int wid = tid >> 6, lane = tid & 63, nw = nthr >> 6;
      for (int i = wid; i < aliveN; i += nw) {
        const int cv = (r == 0) ? i : lin[i];
        if (c.state[cv] != 0) continue;  // stale (killed last round)
        const unsigned long long pc = c.pri[cv];
        const int* row = c.neighs + (long long)cv * K;
        for (int j = lane; j < K; j += 64) {
          const int u = row[j];
          if (c.pri[u] > pc) c.blocked_tag[u] = r;
        }
      }
    }
    if (tid == 0) c.cnt[(r + 1) & 1] = 0;  // counter not read again until latched value is stale
    __threadfence();
    grid.sync();

    // phase C: decide centres, grab, compact survivors
    for (int i = tid; i < aliveN; i += nthr) {
      const int u = (r == 0) ? i : lin[i];
      if (c.state[u] != 0) continue;
      if (c.blocked_tag[u] != r) {
        // centre: no undecided earlier in-neighbour remains
        c.state[u] = 1;
        const unsigned long long pu = c.pri[u];
        const int slot = atomicAdd(&c.cnt[2], 1);
        c.centre_v[slot] = u;
        c.centre_pri[slot] = pu;
        atomicAdd(&c.cnt[4 + (int)(pu >> (IDX_BITS + 32))], 1);
        const int* row = c.neighs + (long long)u * K;
        for (int j = 0; j < K; ++j) {
          const int w = row[j];
          const unsigned long long pw = c.pri[w];
          if (pw > pu) {
            atomicMin(&c.assign_pri[w], pu);  // earliest grabber wins (commutative)
            c.state[w] = 2;                   // w provably not a centre this round -> race-free
          }
        }
      } else {
        const int slot = atomicAdd(&c.cnt[(r + 1) & 1], 1);
        lout[slot] = u;  // may be stale-killed this round; re-filtered next round
      }
    }
    __threadfence();
    grid.sync();
    aliveN = c.cnt[(r + 1) & 1];
    ++r;
    if (aliveN == 0 || r >= 3000) break;
  }

  // ---------------- centre ranks (O(nC^2) LDS-tiled counting) ----------------
  const int nC = c.cnt[2];
  {
    __shared__ unsigned long long shp[256];
    int nMine = 0;
    int myIdx[4];
    unsigned long long myPri[4];
    int myCnt[4];
    for (int i = tid; i < nC && nMine < 4; i += nthr) {
      myIdx[nMine] = i;
      myPri[nMine] = c.centre_pri[i];
      myCnt[nMine] = 0;
      ++nMine;
    }
    for (int cs = 0; cs < nC; cs += 256) {
      const int j = cs + threadIdx.x;
      shp[threadIdx.x] = (j < nC) ? c.centre_pri[j] : ~0ull;
      __syncthreads();
      const int lim = min(256, nC - cs);
      for (int t = 0; t < lim; ++t) {
        const unsigned long long pj = shp[t];
        for (int m = 0; m < nMine; ++m) myCnt[m] += (pj < myPri[m]) ? 1 : 0;
      }
      __syncthreads();
    }
    for (int m = 0; m < nMine; ++m) {
      const int pos = myCnt[m];  // rank among centres by pri == global cumsum rank
      const int vtx = c.centre_v[myIdx[m]];
      c.out_sel[pos] = vtx;
      c.rank_of[vtx] = pos;
    }
  }
  if (tid == 0) {
    int run = 0;
    c.out_rs[0] = 0;
    for (int s = 0; s < c.nseg; ++s) {
      run += c.cnt[4 + s];
      c.out_rs[s + 1] = run;
    }
  }
  __threadfence();
  grid.sync();

  // ---------------- ggather ----------------
  for (int v = tid; v < V; v += nthr) {
    const int ctr = (c.state[v] == 1) ? v : (int)(c.assign_pri[v] & IDX_MASK);
    c.out_gg[v] = c.rank_of[ctr];
  }
}

extern "C" void kernel_launch(void* const* d_in, const int* in_sizes, int n_in,
                              void* d_out, int out_size, void* d_ws, size_t ws_size,
                              hipStream_t stream) {
  Ctx c;
  c.neighs = (const int*)d_in[0];
  c.hier = (const float*)d_in[1];
  c.row_splits = (const int*)d_in[2];
  c.V = in_sizes[1];
  c.K = in_sizes[0] / c.V;
  c.nseg = in_sizes[2] - 1;

  char* p = (char*)d_ws;
  const size_t V = (size_t)c.V;
  c.pri = (unsigned long long*)p; p += V * 8;
  c.assign_pri = (unsigned long long*)p; p += V * 8;
  c.centre_pri = (unsigned long long*)p; p += V * 8;
  c.blocked_tag = (int*)p; p += V * 4;
  c.state = (int*)p; p += V * 4;
  c.listA = (int*)p; p += V * 4;
  c.listB = (int*)p; p += V * 4;
  c.centre_v = (int*)p; p += V * 4;
  c.rank_of = (int*)p; p += V * 4;
  c.cnt = (int*)p; p += 64 * 4;

  int* out = (int*)d_out;
  c.out_sel = out;
  c.out_rs = out + c.V;
  c.out_gg = out + c.V + c.nseg + 1;

  void* args[] = { &c };
  hipLaunchCooperativeKernel((void*)cluster_kernel, dim3(256), dim3(256), args, 0, stream);
}